// Round 10
// baseline (241.491 us; speedup 1.0000x reference)
//
#include <hip/hip_runtime.h>
#include <hip/hip_bf16.h>

// Problem: B=8, T=4096, D=64, K=1024. N = B*T = 32768 rows.
// Inputs:  d_in[0] = x (f32, 2097152), d_in[1] = embeddings (f32, [D][K] = 64x1024)
// Output: FLOAT32, concatenated: quantized (2097152) | encodings (33554432) | indices (32768) | loss (1)
//
// Score s[n,k] = x_n . e_k - 0.5||e_k||^2  (argmax == argmin distance).
// k2: split-fp16 3-MFMA (error ~6e-5); rows with top2-gap <= 0.02 rescanned exactly in f32.

#define NROWS 32768
#define DDIM  64
#define KCB   1024

typedef float    f32x4  __attribute__((ext_vector_type(4)));
typedef _Float16 f16x8  __attribute__((ext_vector_type(8)));

// ws layout (f32 index):
#define WS_ET    0         // Et f32 [k][64]            (65536)
#define WS_H     65536     // 0.5*||e_k||^2             (1024)
#define WS_PART  66560     // loss partials             (2048)
#define WS_IBEST 68608     // final index per row (int) (32768)
#define WS_LIST  101376    // rescan row list (int)     (32768)
#define WS_CTR   134144    // rescan counter (int)      (4 slots)
#define WS_EHI   134148    // E hi fp16, permuted [k][64]  (32768 f32 slots)
#define WS_ELO   166916    // E lo fp16, permuted [k][64]  (32768 f32 slots)
// end: 199684 f32 = 800 KB

// K1: Et f32 [k][d]; permuted split-fp16 Ehi/Elo; h; zero rescan ctr.
// slot p (0..31) of window w holds d = w*32 + 4*(p>>3) + (p&3) + 16*((p>>2)&1).
__global__ __launch_bounds__(256) void k1_prep(const float* __restrict__ E,
                                               float* __restrict__ Et,
                                               float* __restrict__ h,
                                               _Float16* __restrict__ Ehi,
                                               _Float16* __restrict__ Elo,
                                               int* __restrict__ ctr) {
  int k = blockIdx.x * 256 + threadIdx.x;   // 0..1023
  float col[DDIM];
  float sum = 0.f;
#pragma unroll
  for (int d = 0; d < DDIM; ++d) {
    float v = E[d * KCB + k];               // coalesced across lanes
    col[d] = v;
    sum = fmaf(v, v, sum);
  }
  float4* dst = (float4*)(Et + (size_t)k * DDIM);
#pragma unroll
  for (int i = 0; i < 16; ++i)
    dst[i] = make_float4(col[4*i], col[4*i+1], col[4*i+2], col[4*i+3]);
  h[k] = 0.5f * sum;

#pragma unroll
  for (int w = 0; w < 2; ++w) {
#pragma unroll
    for (int p = 0; p < 32; ++p) {
      int dl = w * 32 + 4 * (p >> 3) + (p & 3) + 16 * ((p >> 2) & 1);
      float v = col[dl];
      _Float16 hi = (_Float16)v;
      _Float16 lo = (_Float16)(v - (float)hi);
      Ehi[(size_t)k * DDIM + w * 32 + p] = hi;
      Elo[(size_t)k * DDIM + w * 32 + p] = lo;
    }
  }
  if (k == 0) ctr[0] = 0;
}

// K2: MFMA coarse scores + argmax. Wave = 32 rows x 1024 codes.
// 256 blocks x 256 thr (4 waves = 128 rows/block).
__global__ __launch_bounds__(256, 4) void k2_coarse(const float* __restrict__ x,
                                                    const _Float16* __restrict__ Ehi,
                                                    const _Float16* __restrict__ Elo,
                                                    const float* __restrict__ h,
                                                    int* __restrict__ ibest,
                                                    int* __restrict__ ctr,
                                                    int* __restrict__ list) {
  int tid = threadIdx.x;
  int lane = tid & 63, wid = tid >> 6;
  int g = lane >> 4, c = lane & 15;
  int n0 = (blockIdx.x * 4 + wid) * 32;

  // A-fragments: rows r*16 + c, slots (g,e) hold d = w*32 + 4g + (e&3) + 16*(e>>2)
  f16x8 Ahi[2][2], Alo[2][2];            // [r][w], fully unrolled below
#pragma unroll
  for (int r = 0; r < 2; ++r) {
    const float* xb = x + (size_t)(n0 + r * 16 + c) * DDIM;
#pragma unroll
    for (int w = 0; w < 2; ++w) {
      f32x4 xa = *(const f32x4*)(xb + w * 32 + 4 * g);        // elems 0..3
      f32x4 xc = *(const f32x4*)(xb + w * 32 + 16 + 4 * g);   // elems 4..7
#pragma unroll
      for (int e = 0; e < 4; ++e) {
        _Float16 hi = (_Float16)xa[e];
        Ahi[r][w][e] = hi;
        Alo[r][w][e] = (_Float16)(xa[e] - (float)hi);
      }
#pragma unroll
      for (int e = 0; e < 4; ++e) {
        _Float16 hi = (_Float16)xc[e];
        Ahi[r][w][4 + e] = hi;
        Alo[r][w][4 + e] = (_Float16)(xc[e] - (float)hi);
      }
    }
  }

  float b1[2][4], b2[2][4];
  int   i1[2][4];
#pragma unroll
  for (int r = 0; r < 2; ++r)
#pragma unroll
    for (int q = 0; q < 4; ++q) { b1[r][q] = -3.0e38f; b2[r][q] = -3.0e38f; i1[r][q] = 0; }

  const _Float16* peh = Ehi + c * DDIM + g * 8;
  const _Float16* pel = Elo + c * DDIM + g * 8;

  // prefetch chunk 0
  f16x8 bh0n = *(const f16x8*)(peh);
  f16x8 bl0n = *(const f16x8*)(pel);
  f16x8 bh1n = *(const f16x8*)(peh + 32);
  f16x8 bl1n = *(const f16x8*)(pel + 32);
  float hn = h[c];

  for (int ch = 0; ch < 64; ++ch) {
    f16x8 bh0 = bh0n, bl0 = bl0n, bh1 = bh1n, bl1 = bl1n;
    float hc = hn;
    if (ch < 63) {
      size_t off = (size_t)(ch + 1) * 16 * DDIM;
      bh0n = *(const f16x8*)(peh + off);
      bl0n = *(const f16x8*)(pel + off);
      bh1n = *(const f16x8*)(peh + off + 32);
      bl1n = *(const f16x8*)(pel + off + 32);
      hn = h[(ch + 1) * 16 + c];
    }
    int code = ch * 16 + c;
#pragma unroll
    for (int r = 0; r < 2; ++r) {
      f32x4 a = { -hc, -hc, -hc, -hc };
      a = __builtin_amdgcn_mfma_f32_16x16x32_f16(Alo[r][0], bh0, a, 0, 0, 0);
      a = __builtin_amdgcn_mfma_f32_16x16x32_f16(Ahi[r][0], bl0, a, 0, 0, 0);
      a = __builtin_amdgcn_mfma_f32_16x16x32_f16(Ahi[r][0], bh0, a, 0, 0, 0);
      a = __builtin_amdgcn_mfma_f32_16x16x32_f16(Alo[r][1], bh1, a, 0, 0, 0);
      a = __builtin_amdgcn_mfma_f32_16x16x32_f16(Ahi[r][1], bl1, a, 0, 0, 0);
      a = __builtin_amdgcn_mfma_f32_16x16x32_f16(Ahi[r][1], bh1, a, 0, 0, 0);
#pragma unroll
      for (int q = 0; q < 4; ++q) {
        float s = a[q];
        bool gt = s > b1[r][q];
        b2[r][q] = gt ? b1[r][q] : fmaxf(b2[r][q], s);
        i1[r][q] = gt ? code : i1[r][q];
        b1[r][q] = gt ? s : b1[r][q];
      }
    }
  }

  // reduce (b1,i1,b2) across the 16 code-lanes (same g), lex tie-break to smaller index
#pragma unroll
  for (int step = 1; step <= 8; step <<= 1) {
#pragma unroll
    for (int r = 0; r < 2; ++r)
#pragma unroll
      for (int q = 0; q < 4; ++q) {
        float ob1 = __shfl_xor(b1[r][q], step);
        int   oi1 = __shfl_xor(i1[r][q], step);
        float ob2 = __shfl_xor(b2[r][q], step);
        bool win = (ob1 > b1[r][q]) || (ob1 == b1[r][q] && oi1 < i1[r][q]);
        float loser = win ? b1[r][q] : ob1;
        b1[r][q] = win ? ob1 : b1[r][q];
        i1[r][q] = win ? oi1 : i1[r][q];
        b2[r][q] = fmaxf(fmaxf(b2[r][q], ob2), loser);
      }
  }

  if (c == 0) {                       // lanes 0,16,32,48: rows 4g+q of each rowgroup
#pragma unroll
    for (int r = 0; r < 2; ++r)
#pragma unroll
      for (int q = 0; q < 4; ++q) {
        int row = n0 + r * 16 + 4 * g + q;
        ibest[row] = i1[r][q];
        if (b1[r][q] - b2[r][q] <= 0.02f) {   // provably-safe margin >> 6e-5 error bound
          int p = atomicAdd(ctr, 1);
          list[p] = row;
        }
      }
  }
}

// K2b: exact f32 rescan of flagged rows. One wave per row; lane covers 16 codes.
__global__ __launch_bounds__(256) void k2b_rescan(const float* __restrict__ x,
                                                  const float* __restrict__ Et,
                                                  const float* __restrict__ h,
                                                  const int* __restrict__ ctr,
                                                  const int* __restrict__ list,
                                                  int* __restrict__ ibest) {
  int lane = threadIdx.x & 63;
  int w = blockIdx.x * 4 + (threadIdx.x >> 6);
  int cnt = ctr[0];
  for (int i = w; i < cnt; i += 512) {
    int n = list[i];
    const f32x4* xr = (const f32x4*)(x + (size_t)n * DDIM);
    f32x4 xv[16];
#pragma unroll
    for (int d = 0; d < 16; ++d) xv[d] = xr[d];   // broadcast loads
    float best = -3.0e38f; int bi = 0;
    for (int j = 0; j < 16; ++j) {
      int code = j * 64 + lane;
      const f32x4* er = (const f32x4*)(Et + (size_t)code * DDIM);
      float acc = -h[code];
#pragma unroll
      for (int d = 0; d < 16; ++d) {
        f32x4 e4 = er[d], x4 = xv[d];
        acc = fmaf(x4[0], e4[0], acc); acc = fmaf(x4[1], e4[1], acc);
        acc = fmaf(x4[2], e4[2], acc); acc = fmaf(x4[3], e4[3], acc);
      }
      if (acc > best || (acc == best && code < bi)) { best = acc; bi = code; }
    }
#pragma unroll
    for (int step = 1; step <= 32; step <<= 1) {
      float ob = __shfl_xor(best, step);
      int   oi = __shfl_xor(bi, step);
      if (ob > best || (ob == best && oi < bi)) { best = ob; bi = oi; }
    }
    if (lane == 0) ibest[n] = bi;
  }
}

// K34 fused: indices, quantized (1 float4/thread), loss partial, one-hot stream.
__global__ __launch_bounds__(256) void k34_fused(const float* __restrict__ x,
                                                 const float* __restrict__ Et,
                                                 const int* __restrict__ ibest,
                                                 float* __restrict__ partial,
                                                 float* __restrict__ out_q,
                                                 float* __restrict__ out_enc,
                                                 float* __restrict__ out_ind) {
  __shared__ int sidx[16];
  int tid = threadIdx.x;
  int r0 = blockIdx.x * 16;

  if (tid < 16) {
    int n = r0 + tid;
    int bi = ibest[n];
    sidx[tid] = bi;
    out_ind[n] = (float)bi;
  }
  __syncthreads();

  int r = tid >> 4, cc = tid & 15;
  int n = r0 + r;
  int bi = sidx[r];
  float4 q4 = *(const float4*)(Et + (size_t)bi * DDIM + cc * 4);  // L2-resident gather
  float4 x4 = *(const float4*)(x + (size_t)n * DDIM + cc * 4);    // coalesced
  float d0 = q4.x - x4.x, d1 = q4.y - x4.y, d2 = q4.z - x4.z, d3 = q4.w - x4.w;
  float lsum = 0.f;
  lsum = fmaf(d0, d0, lsum); lsum = fmaf(d1, d1, lsum);
  lsum = fmaf(d2, d2, lsum); lsum = fmaf(d3, d3, lsum);
  *(float4*)(out_q + (size_t)n * DDIM + cc * 4) = q4;

#pragma unroll
  for (int rr = 0; rr < 16; ++rr) {
    int bk = sidx[rr];
    f32x4 v = (f32x4)(0.f);
    if ((bk >> 2) == tid) v[bk & 3] = 1.0f;
    __builtin_nontemporal_store(v, (f32x4*)(out_enc + (size_t)(r0 + rr) * KCB + tid * 4));
  }

#pragma unroll
  for (int off = 32; off > 0; off >>= 1) lsum += __shfl_down(lsum, off);
  __shared__ float red[4];
  int lane = tid & 63, wv = tid >> 6;
  if (lane == 0) red[wv] = lsum;
  __syncthreads();
  if (tid == 0) partial[blockIdx.x] = red[0] + red[1] + red[2] + red[3];
}

// K5: reduce 2048 partials -> loss.
__global__ void k5_loss(const float* __restrict__ partial, float* __restrict__ out_loss) {
  int t = threadIdx.x;                 // 256 threads
  float s = 0.f;
#pragma unroll
  for (int i = 0; i < 8; ++i) s += partial[t + i * 256];
#pragma unroll
  for (int off = 32; off > 0; off >>= 1) s += __shfl_down(s, off);
  __shared__ float red[4];
  int lane = t & 63, w = t >> 6;
  if (lane == 0) red[w] = s;
  __syncthreads();
  if (t == 0) out_loss[0] = (red[0] + red[1] + red[2] + red[3]) * (1.0f / 2097152.0f);
}

extern "C" void kernel_launch(void* const* d_in, const int* in_sizes, int n_in,
                              void* d_out, int out_size, void* d_ws, size_t ws_size,
                              hipStream_t stream) {
  const float* x = (const float*)d_in[0];
  const float* E = (const float*)d_in[1];

  float* ws    = (float*)d_ws;
  float* Et    = ws + WS_ET;
  float* h     = ws + WS_H;
  float* part  = ws + WS_PART;
  int*   ibest = (int*)(ws + WS_IBEST);
  int*   list  = (int*)(ws + WS_LIST);
  int*   ctr   = (int*)(ws + WS_CTR);
  _Float16* Ehi = (_Float16*)(ws + WS_EHI);
  _Float16* Elo = (_Float16*)(ws + WS_ELO);

  float* out      = (float*)d_out;
  float* out_q    = out;                      // 2097152
  float* out_enc  = out + 2097152;            // 33554432
  float* out_ind  = out + 35651584;           // 32768
  float* out_loss = out + 35684352;           // 1

  k1_prep<<<4, 256, 0, stream>>>(E, Et, h, Ehi, Elo, ctr);
  k2_coarse<<<256, 256, 0, stream>>>(x, Ehi, Elo, h, ibest, ctr, list);
  k2b_rescan<<<128, 256, 0, stream>>>(x, Et, h, ctr, list, ibest);
  k34_fused<<<2048, 256, 0, stream>>>(x, Et, ibest, part, out_q, out_enc, out_ind);
  k5_loss<<<1, 256, 0, stream>>>(part, out_loss);
}

// Round 11
// 220.302 us; speedup vs baseline: 1.0962x; 1.0962x over previous
//
#include <hip/hip_runtime.h>
#include <hip/hip_bf16.h>

// Problem: B=8, T=4096, D=64, K=1024. N = B*T = 32768 rows.
// Inputs:  d_in[0] = x (f32, 2097152), d_in[1] = embeddings (f32, [D][K])
// Output (f32): quantized (2097152) | encodings (33554432) | indices (32768) | loss (1)
//
// Score s[n,k] = x_n.e_k - 0.5||e_k||^2 (argmax == argmin distance).
// Split-fp16 3-MFMA coarse scores (err ~1e-4); rows with top2-gap <= 0.02
// rescanned exactly in f32 inside the same block. Everything fused into one
// main kernel bound by the compulsory 142.7 MB output stream.

#define NROWS 32768
#define DDIM  64
#define KCB   1024
#define MARGIN 0.02f

typedef float    f32x4 __attribute__((ext_vector_type(4)));
typedef _Float16 f16x8 __attribute__((ext_vector_type(8)));

// ws layout (f32 index):
#define WS_ET    0         // Et f32 [k][64]             (65536)
#define WS_H     65536     // 0.5*||e_k||^2              (1024)
#define WS_PART  66560     // loss partials              (1024)
#define WS_EHI   67584     // E hi fp16 permuted [k][64] (32768 f32 slots)
#define WS_ELO   100352    // E lo fp16 permuted [k][64] (32768 f32 slots)
// end: 133120 f32 = 532 KB

// K_A: Et f32 [k][d]; permuted split-fp16 Ehi/Elo (packed 16-B stores); h.
// slot p (0..31) of window w holds d = w*32 + 4*(p>>3) + (p&3) + 16*((p>>2)&1).
__global__ __launch_bounds__(64) void kA_prep(const float* __restrict__ E,
                                              float* __restrict__ Et,
                                              float* __restrict__ h,
                                              _Float16* __restrict__ Ehi,
                                              _Float16* __restrict__ Elo) {
  int k = blockIdx.x * 64 + threadIdx.x;    // 0..1023
  float col[DDIM];
  float sum = 0.f;
#pragma unroll
  for (int d = 0; d < DDIM; ++d) {
    float v = E[d * KCB + k];               // coalesced across lanes
    col[d] = v;
    sum = fmaf(v, v, sum);
  }
  float4* dst = (float4*)(Et + (size_t)k * DDIM);
#pragma unroll
  for (int i = 0; i < 16; ++i)
    dst[i] = make_float4(col[4*i], col[4*i+1], col[4*i+2], col[4*i+3]);
  h[k] = 0.5f * sum;

#pragma unroll
  for (int w = 0; w < 2; ++w) {
    f16x8 hi8[4], lo8[4];
#pragma unroll
    for (int p = 0; p < 32; ++p) {
      int dl = w * 32 + 4 * (p >> 3) + (p & 3) + 16 * ((p >> 2) & 1);
      float v = col[dl];
      _Float16 hi = (_Float16)v;
      hi8[p >> 3][p & 7] = hi;
      lo8[p >> 3][p & 7] = (_Float16)(v - (float)hi);
    }
#pragma unroll
    for (int q = 0; q < 4; ++q) {
      *(f16x8*)(Ehi + (size_t)k * DDIM + w * 32 + q * 8) = hi8[q];
      *(f16x8*)(Elo + (size_t)k * DDIM + w * 32 + q * 8) = lo8[q];
    }
  }
}

// K_B: fused main kernel. Block = 128 thr (2 waves) = 32 rows.
// Wave ws covers codes [ws*512, ws*512+512); r10-verified MFMA fragment flow.
__global__ __launch_bounds__(128, 2) void kB_main(const float* __restrict__ x,
                                                  const _Float16* __restrict__ Ehi,
                                                  const _Float16* __restrict__ Elo,
                                                  const float* __restrict__ Et,
                                                  const float* __restrict__ h,
                                                  float* __restrict__ partial,
                                                  float* __restrict__ out_q,
                                                  float* __restrict__ out_enc,
                                                  float* __restrict__ out_ind) {
  __shared__ float mb1[2][32], mb2[2][32];
  __shared__ int   mi1[2][32];
  __shared__ int   sidx[32];
  __shared__ int   flags[32];
  __shared__ int   nflag;
  __shared__ float rb[2];
  __shared__ int   ri[2];
  __shared__ float red[2];

  int tid  = threadIdx.x;
  int ws   = tid >> 6;               // wave 0/1 -> K-half
  int lane = tid & 63;
  int g = lane >> 4, c = lane & 15;
  int r0 = blockIdx.x * 32;

  if (tid == 0) nflag = 0;

  // A-fragments for rows r0 + r*16 + c (r=0,1), slots d = w*32+4g+(e&3)+16*(e>>2)
  f16x8 Ahi[2][2], Alo[2][2];
#pragma unroll
  for (int r = 0; r < 2; ++r) {
    const float* xb = x + (size_t)(r0 + r * 16 + c) * DDIM;
#pragma unroll
    for (int w = 0; w < 2; ++w) {
      f32x4 xa = *(const f32x4*)(xb + w * 32 + 4 * g);
      f32x4 xc = *(const f32x4*)(xb + w * 32 + 16 + 4 * g);
#pragma unroll
      for (int e = 0; e < 4; ++e) {
        _Float16 hi = (_Float16)xa[e];
        Ahi[r][w][e] = hi;
        Alo[r][w][e] = (_Float16)(xa[e] - (float)hi);
      }
#pragma unroll
      for (int e = 0; e < 4; ++e) {
        _Float16 hi = (_Float16)xc[e];
        Ahi[r][w][4 + e] = hi;
        Alo[r][w][4 + e] = (_Float16)(xc[e] - (float)hi);
      }
    }
  }

  float b1[2][4], b2[2][4];
  int   i1[2][4];
#pragma unroll
  for (int r = 0; r < 2; ++r)
#pragma unroll
    for (int q = 0; q < 4; ++q) { b1[r][q] = -3.0e38f; b2[r][q] = -3.0e38f; i1[r][q] = 0; }

  const _Float16* peh = Ehi + (size_t)(ws * 512 + c) * DDIM + g * 8;
  const _Float16* pel = Elo + (size_t)(ws * 512 + c) * DDIM + g * 8;

  f16x8 bh0n = *(const f16x8*)(peh);
  f16x8 bl0n = *(const f16x8*)(pel);
  f16x8 bh1n = *(const f16x8*)(peh + 32);
  f16x8 bl1n = *(const f16x8*)(pel + 32);
  float hn = h[ws * 512 + c];

  for (int ch = 0; ch < 32; ++ch) {
    f16x8 bh0 = bh0n, bl0 = bl0n, bh1 = bh1n, bl1 = bl1n;
    float hc = hn;
    if (ch < 31) {
      size_t off = (size_t)(ch + 1) * 16 * DDIM;
      bh0n = *(const f16x8*)(peh + off);
      bl0n = *(const f16x8*)(pel + off);
      bh1n = *(const f16x8*)(peh + off + 32);
      bl1n = *(const f16x8*)(pel + off + 32);
      hn = h[ws * 512 + (ch + 1) * 16 + c];
    }
    int code = ws * 512 + ch * 16 + c;
#pragma unroll
    for (int r = 0; r < 2; ++r) {
      f32x4 a = { -hc, -hc, -hc, -hc };
      a = __builtin_amdgcn_mfma_f32_16x16x32_f16(Alo[r][0], bh0, a, 0, 0, 0);
      a = __builtin_amdgcn_mfma_f32_16x16x32_f16(Ahi[r][0], bl0, a, 0, 0, 0);
      a = __builtin_amdgcn_mfma_f32_16x16x32_f16(Ahi[r][0], bh0, a, 0, 0, 0);
      a = __builtin_amdgcn_mfma_f32_16x16x32_f16(Alo[r][1], bh1, a, 0, 0, 0);
      a = __builtin_amdgcn_mfma_f32_16x16x32_f16(Ahi[r][1], bl1, a, 0, 0, 0);
      a = __builtin_amdgcn_mfma_f32_16x16x32_f16(Ahi[r][1], bh1, a, 0, 0, 0);
#pragma unroll
      for (int q = 0; q < 4; ++q) {
        float s = a[q];
        bool gt = s > b1[r][q];
        b2[r][q] = gt ? b1[r][q] : fmaxf(b2[r][q], s);
        i1[r][q] = gt ? code : i1[r][q];
        b1[r][q] = gt ? s : b1[r][q];
      }
    }
  }

  // reduce across the 16 code-lanes (same g), lex tie-break to smaller index
#pragma unroll
  for (int step = 1; step <= 8; step <<= 1) {
#pragma unroll
    for (int r = 0; r < 2; ++r)
#pragma unroll
      for (int q = 0; q < 4; ++q) {
        float ob1 = __shfl_xor(b1[r][q], step);
        int   oi1 = __shfl_xor(i1[r][q], step);
        float ob2 = __shfl_xor(b2[r][q], step);
        bool win = (ob1 > b1[r][q]) || (ob1 == b1[r][q] && oi1 < i1[r][q]);
        float loser = win ? b1[r][q] : ob1;
        b1[r][q] = win ? ob1 : b1[r][q];
        i1[r][q] = win ? oi1 : i1[r][q];
        b2[r][q] = fmaxf(fmaxf(b2[r][q], ob2), loser);
      }
  }
  if (c == 0) {
#pragma unroll
    for (int r = 0; r < 2; ++r)
#pragma unroll
      for (int q = 0; q < 4; ++q) {
        int row = r * 16 + 4 * g + q;
        mb1[ws][row] = b1[r][q];
        mi1[ws][row] = i1[r][q];
        mb2[ws][row] = b2[r][q];
      }
  }
  __syncthreads();

  // merge the two K-halves; flag near-ties for exact rescan
  if (tid < 32) {
    float a1 = mb1[0][tid], a2 = mb1[1][tid];
    int   j1 = mi1[0][tid], j2 = mi1[1][tid];
    bool w1 = (a2 > a1) || (a2 == a1 && j2 < j1);
    float bb1 = w1 ? a2 : a1;
    int   ii1 = w1 ? j2 : j1;
    float bb2 = fmaxf(fmaxf(mb2[0][tid], mb2[1][tid]), w1 ? a1 : a2);
    sidx[tid] = ii1;
    if (bb1 - bb2 <= MARGIN) { int p = atomicAdd(&nflag, 1); flags[p] = tid; }
  }
  __syncthreads();

  // exact f32 rescan of flagged rows (rare), whole block per row
  int nf = nflag;
  for (int fi = 0; fi < nf; ++fi) {
    int row = flags[fi];
    int n = r0 + row;
    const f32x4* xr = (const f32x4*)(x + (size_t)n * DDIM);
    f32x4 xv[16];
#pragma unroll
    for (int d = 0; d < 16; ++d) xv[d] = xr[d];        // broadcast loads
    float best = -3.0e38f; int bi = 0;
#pragma unroll 1
    for (int j = 0; j < 8; ++j) {
      int code = j * 128 + tid;
      const f32x4* er = (const f32x4*)(Et + (size_t)code * DDIM);
      float acc = -h[code];
#pragma unroll
      for (int d = 0; d < 16; ++d) {
        f32x4 e4 = er[d], x4 = xv[d];
        acc = fmaf(x4[0], e4[0], acc); acc = fmaf(x4[1], e4[1], acc);
        acc = fmaf(x4[2], e4[2], acc); acc = fmaf(x4[3], e4[3], acc);
      }
      if (acc > best || (acc == best && code < bi)) { best = acc; bi = code; }
    }
#pragma unroll
    for (int step = 1; step <= 32; step <<= 1) {
      float ob = __shfl_xor(best, step);
      int   oi = __shfl_xor(bi, step);
      if (ob > best || (ob == best && oi < bi)) { best = ob; bi = oi; }
    }
    if (lane == 0) { rb[ws] = best; ri[ws] = bi; }
    __syncthreads();
    if (tid == 0) {
      bool w1 = (rb[1] > rb[0]) || (rb[1] == rb[0] && ri[1] < ri[0]);
      sidx[row] = w1 ? ri[1] : ri[0];
    }
    __syncthreads();
  }

  // ---- outputs ----
  if (tid < 32) out_ind[r0 + tid] = (float)sidx[tid];

  // quantized + loss: 512 float4 chunks over 128 threads
  float lsum = 0.f;
#pragma unroll
  for (int i = 0; i < 4; ++i) {
    int f = tid + i * 128;
    int row = f >> 4, cc = f & 15;
    int n = r0 + row;
    int bi = sidx[row];
    f32x4 q4 = *(const f32x4*)(Et + (size_t)bi * DDIM + cc * 4);
    f32x4 x4 = *(const f32x4*)(x + (size_t)n * DDIM + cc * 4);
    float d0 = q4[0] - x4[0], d1 = q4[1] - x4[1], d2 = q4[2] - x4[2], d3 = q4[3] - x4[3];
    lsum = fmaf(d0, d0, lsum); lsum = fmaf(d1, d1, lsum);
    lsum = fmaf(d2, d2, lsum); lsum = fmaf(d3, d3, lsum);
    __builtin_nontemporal_store(q4, (f32x4*)(out_q + (size_t)n * DDIM + cc * 4));
  }

  // one-hot encodings: per row, 256 float4 over 128 threads (2 each)
#pragma unroll 1
  for (int rr = 0; rr < 32; ++rr) {
    int bk = sidx[rr];
    float* rowp = out_enc + (size_t)(r0 + rr) * KCB;
#pragma unroll
    for (int i = 0; i < 2; ++i) {
      int slot = tid + i * 128;
      f32x4 v = (f32x4)(0.f);
      if ((bk >> 2) == slot) v[bk & 3] = 1.0f;
      __builtin_nontemporal_store(v, (f32x4*)(rowp + slot * 4));
    }
  }

  // loss partial: shfl within wave -> LDS -> plain store
#pragma unroll
  for (int off = 32; off > 0; off >>= 1) lsum += __shfl_down(lsum, off);
  if (lane == 0) red[ws] = lsum;
  __syncthreads();
  if (tid == 0) partial[blockIdx.x] = red[0] + red[1];
}

// K5: reduce 1024 partials -> loss.
__global__ void k5_loss(const float* __restrict__ partial, float* __restrict__ out_loss) {
  int t = threadIdx.x;                 // 256 threads
  float s = 0.f;
#pragma unroll
  for (int i = 0; i < 4; ++i) s += partial[t + i * 256];
#pragma unroll
  for (int off = 32; off > 0; off >>= 1) s += __shfl_down(s, off);
  __shared__ float red[4];
  int lane = t & 63, w = t >> 6;
  if (lane == 0) red[w] = s;
  __syncthreads();
  if (t == 0) out_loss[0] = (red[0] + red[1] + red[2] + red[3]) * (1.0f / 2097152.0f);
}

extern "C" void kernel_launch(void* const* d_in, const int* in_sizes, int n_in,
                              void* d_out, int out_size, void* d_ws, size_t ws_size,
                              hipStream_t stream) {
  const float* x = (const float*)d_in[0];
  const float* E = (const float*)d_in[1];

  float* ws   = (float*)d_ws;
  float* Et   = ws + WS_ET;
  float* h    = ws + WS_H;
  float* part = ws + WS_PART;
  _Float16* Ehi = (_Float16*)(ws + WS_EHI);
  _Float16* Elo = (_Float16*)(ws + WS_ELO);

  float* out      = (float*)d_out;
  float* out_q    = out;                      // 2097152
  float* out_enc  = out + 2097152;            // 33554432
  float* out_ind  = out + 35651584;           // 32768
  float* out_loss = out + 35684352;           // 1

  kA_prep<<<16, 64, 0, stream>>>(E, Et, h, Ehi, Elo);
  kB_main<<<1024, 128, 0, stream>>>(x, Ehi, Elo, Et, h, part, out_q, out_enc, out_ind);
  k5_loss<<<1, 256, 0, stream>>>(part, out_loss);
}